// Round 1
// baseline (593.255 us; speedup 1.0000x reference)
//
#include <hip/hip_runtime.h>

#define D 96
#define MROWS 32       // rows per MLP block
#define TSTR 100       // padded LDS row stride (floats): 400B, 16B-aligned, not mult-of-32
#define SCANB 512      // scan1 block size

// ---------------- copy x into out[:, 0:96] ----------------
__global__ void k_copyx(const float* __restrict__ x, float* __restrict__ out, int n) {
    int idx = blockIdx.x * blockDim.x + threadIdx.x;   // n*24 float4s
    if (idx >= n * 24) return;
    int r = idx / 24, c = idx - r * 24;
    ((float4*)out)[r * 96 + c] = ((const float4*)x)[r * 24 + c];   // out row = 384 floats = 96 float4
}

// ---------------- CSR build ----------------
__global__ void k_hist(const int* __restrict__ dst, int* __restrict__ deg, int E) {
    int e = blockIdx.x * blockDim.x + threadIdx.x;
    if (e < E) atomicAdd(&deg[dst[e]], 1);
}

__global__ __launch_bounds__(SCANB) void k_scan1(const int* __restrict__ deg,
                                                 int* __restrict__ rowstart,
                                                 int* __restrict__ bsum, int n) {
    __shared__ int s[SCANB];
    int idx = threadIdx.x, gid = blockIdx.x * SCANB + idx;
    int v = (gid < n) ? deg[gid] : 0;
    s[idx] = v;
    __syncthreads();
    for (int off = 1; off < SCANB; off <<= 1) {
        int u = (idx >= off) ? s[idx - off] : 0;
        __syncthreads();
        s[idx] += u;
        __syncthreads();
    }
    if (gid < n) rowstart[gid] = s[idx] - v;            // exclusive within block
    if (idx == SCANB - 1) bsum[blockIdx.x] = s[idx];    // block total
}

__global__ void k_scan2(const int* __restrict__ bsum, int* __restrict__ boff, int nb) {
    __shared__ int s[128];
    int idx = threadIdx.x;
    int v = (idx < nb) ? bsum[idx] : 0;
    s[idx] = v;
    __syncthreads();
    for (int off = 1; off < 128; off <<= 1) {
        int u = (idx >= off) ? s[idx - off] : 0;
        __syncthreads();
        s[idx] += u;
        __syncthreads();
    }
    if (idx < nb) boff[idx] = s[idx] - v;               // exclusive across blocks
}

__global__ void k_scan3(int* __restrict__ rowstart, int* __restrict__ cursor,
                        const int* __restrict__ boff, int n, int E) {
    int gid = blockIdx.x * blockDim.x + threadIdx.x;
    if (gid < n) {
        int v = rowstart[gid] + boff[gid >> 9];         // >>9 == /SCANB
        rowstart[gid] = v;
        cursor[gid] = v;
    }
    if (gid == 0) rowstart[n] = E;
}

__global__ void k_fill(const int* __restrict__ src, const int* __restrict__ dst,
                       int* __restrict__ cursor, int* __restrict__ ecsr, int E) {
    int e = blockIdx.x * blockDim.x + threadIdx.x;
    if (e < E) {
        int p = atomicAdd(&cursor[dst[e]], 1);
        ecsr[p] = src[e];
    }
}

// ---------------- GIN aggregation: t[i] = h[i] + sum_{(s->i)} h[s] ----------------
// 32 lanes per node; lane holds features {lane, lane+32, lane+64}.
__global__ __launch_bounds__(256) void k_aggr(const float* __restrict__ h,
                                              const int* __restrict__ rowstart,
                                              const int* __restrict__ ecsr,
                                              float* __restrict__ t, int n) {
    int g = (blockIdx.x * 256 + threadIdx.x) >> 5;      // node id
    int lane = threadIdx.x & 31;
    if (g >= n) return;
    const float* hp0 = h + (size_t)g * D + lane;
    float a0 = hp0[0], a1 = hp0[32], a2 = hp0[64];      // self term (eps=0)
    int e0 = rowstart[g], e1 = rowstart[g + 1];
    for (int k = e0; k < e1; k++) {
        int s = ecsr[k];
        const float* hp = h + (size_t)s * D + lane;
        a0 += hp[0];
        a1 += hp[32];
        a2 += hp[64];
    }
    float* tp = t + (size_t)g * D + lane;
    tp[0] = a0; tp[32] = a1; tp[64] = a2;
}

// ---------------- fused MLP: h_new = relu(t@W1 + b1)@W2 + b2 ----------------
// Block: 32 rows. LDS: W transposed-quad [j/4][c][4] (lane-consecutive 16B reads),
// tin/y1 row-major stride 100 (broadcast reads, conflict-free writes). 62.5 KB -> 2 blk/CU.
__global__ __launch_bounds__(256, 2) void k_mlp(const float* __restrict__ t,
                                                const float* __restrict__ W1,
                                                const float* __restrict__ B1,
                                                const float* __restrict__ W2,
                                                const float* __restrict__ B2,
                                                float* __restrict__ hbuf,
                                                float* __restrict__ out,
                                                int n, int ocol) {
    __shared__ float wtq[(D / 4) * D * 4];   // 9216 floats
    __shared__ float tin[MROWS * TSTR];      // 3200 floats
    __shared__ float y1s[MROWS * TSTR];      // 3200 floats

    const int tid = threadIdx.x;
    const int row0 = blockIdx.x * MROWS;

    // stage W1 transposed-quad: wtq[(q*D + c)*4 + jj] = W1[(4q+jj)*D + c]
    for (int idx = tid; idx < D * D; idx += 256) {
        int j = idx / D, c = idx - j * D;
        wtq[((j >> 2) * D + c) * 4 + (j & 3)] = W1[idx];
    }
    // stage 32 rows of t
    for (int idx = tid; idx < MROWS * D; idx += 256) {
        int r = idx / D, c = idx - r * D;
        int gr = row0 + r; gr = (gr < n) ? gr : (n - 1);
        tin[r * TSTR + c] = t[(size_t)gr * D + c];
    }
    __syncthreads();

    const int tx = tid & 31, ty = tid >> 5;
    const int r0 = ty * 4;                   // rows r0..r0+3; cols tx, tx+32, tx+64

    float acc[4][3];
    {
        float b0 = B1[tx], b1 = B1[tx + 32], b2 = B1[tx + 64];
        #pragma unroll
        for (int i = 0; i < 4; i++) { acc[i][0] = b0; acc[i][1] = b1; acc[i][2] = b2; }
    }
    #pragma unroll 4
    for (int q = 0; q < D / 4; q++) {
        float4 wv0 = *(const float4*)&wtq[(q * D + tx) * 4];
        float4 wv1 = *(const float4*)&wtq[(q * D + tx + 32) * 4];
        float4 wv2 = *(const float4*)&wtq[(q * D + tx + 64) * 4];
        #pragma unroll
        for (int i = 0; i < 4; i++) {
            float4 av = *(const float4*)&tin[(r0 + i) * TSTR + q * 4];
            acc[i][0] += av.x * wv0.x + av.y * wv0.y + av.z * wv0.z + av.w * wv0.w;
            acc[i][1] += av.x * wv1.x + av.y * wv1.y + av.z * wv1.z + av.w * wv1.w;
            acc[i][2] += av.x * wv2.x + av.y * wv2.y + av.z * wv2.z + av.w * wv2.w;
        }
    }
    // relu -> y1s
    #pragma unroll
    for (int i = 0; i < 4; i++) {
        y1s[(r0 + i) * TSTR + tx]      = fmaxf(acc[i][0], 0.f);
        y1s[(r0 + i) * TSTR + tx + 32] = fmaxf(acc[i][1], 0.f);
        y1s[(r0 + i) * TSTR + tx + 64] = fmaxf(acc[i][2], 0.f);
    }
    __syncthreads();                          // all wtq reads + y1s writes done

    // stage W2
    for (int idx = tid; idx < D * D; idx += 256) {
        int j = idx / D, c = idx - j * D;
        wtq[((j >> 2) * D + c) * 4 + (j & 3)] = W2[idx];
    }
    {
        float b0 = B2[tx], b1 = B2[tx + 32], b2 = B2[tx + 64];
        #pragma unroll
        for (int i = 0; i < 4; i++) { acc[i][0] = b0; acc[i][1] = b1; acc[i][2] = b2; }
    }
    __syncthreads();

    #pragma unroll 4
    for (int q = 0; q < D / 4; q++) {
        float4 wv0 = *(const float4*)&wtq[(q * D + tx) * 4];
        float4 wv1 = *(const float4*)&wtq[(q * D + tx + 32) * 4];
        float4 wv2 = *(const float4*)&wtq[(q * D + tx + 64) * 4];
        #pragma unroll
        for (int i = 0; i < 4; i++) {
            float4 av = *(const float4*)&y1s[(r0 + i) * TSTR + q * 4];
            acc[i][0] += av.x * wv0.x + av.y * wv0.y + av.z * wv0.z + av.w * wv0.w;
            acc[i][1] += av.x * wv1.x + av.y * wv1.y + av.z * wv1.z + av.w * wv1.w;
            acc[i][2] += av.x * wv2.x + av.y * wv2.y + av.z * wv2.z + av.w * wv2.w;
        }
    }

    #pragma unroll
    for (int i = 0; i < 4; i++) {
        int gr = row0 + r0 + i;
        if (gr < n) {
            float* hb = hbuf + (size_t)gr * D + tx;
            float* ob = out + (size_t)gr * 384 + ocol + tx;
            hb[0] = acc[i][0]; hb[32] = acc[i][1]; hb[64] = acc[i][2];
            ob[0] = acc[i][0]; ob[32] = acc[i][1]; ob[64] = acc[i][2];
        }
    }
}

extern "C" void kernel_launch(void* const* d_in, const int* in_sizes, int n_in,
                              void* d_out, int out_size, void* d_ws, size_t ws_size,
                              hipStream_t stream) {
    const float* x = (const float*)d_in[0];
    const int* ei = (const int*)d_in[1];
    const int n = in_sizes[0] / D;           // 50000
    const int E = in_sizes[1] / 2;           // 800000
    const int* src = ei;
    const int* dst = ei + E;
    float* out = (float*)d_out;

    // workspace layout
    float* t    = (float*)d_ws;              // n*D floats
    float* hbuf = t + (size_t)n * D;         // n*D floats
    int*   deg      = (int*)(hbuf + (size_t)n * D);
    int*   rowstart = deg + 50048;           // n+1 entries
    int*   cursor   = rowstart + 50056;
    int*   bsum     = cursor + 50048;
    int*   boff     = bsum + 128;
    int*   ecsr     = boff + 128;            // E entries

    const int nb_scan = (n + SCANB - 1) / SCANB;   // 98

    // out[:,0:96] = x
    k_copyx<<<(n * 24 + 255) / 256, 256, 0, stream>>>(x, out, n);

    // CSR build (once; shared by all 3 layers)
    hipMemsetAsync(deg, 0, (size_t)n * sizeof(int), stream);
    k_hist<<<(E + 255) / 256, 256, 0, stream>>>(dst, deg, E);
    k_scan1<<<nb_scan, SCANB, 0, stream>>>(deg, rowstart, bsum, n);
    k_scan2<<<1, 128, 0, stream>>>(bsum, boff, nb_scan);
    k_scan3<<<(n + 255) / 256, 256, 0, stream>>>(rowstart, cursor, boff, n, E);
    k_fill<<<(E + 255) / 256, 256, 0, stream>>>(src, dst, cursor, ecsr, E);

    const int aggr_grid = (n * 32 + 255) / 256;
    const int mlp_grid  = (n + MROWS - 1) / MROWS;

    for (int l = 0; l < 3; l++) {
        const float* W1 = (const float*)d_in[2 + 4 * l];
        const float* B1 = (const float*)d_in[3 + 4 * l];
        const float* W2 = (const float*)d_in[4 + 4 * l];
        const float* B2 = (const float*)d_in[5 + 4 * l];
        const float* h = (l == 0) ? x : hbuf;
        k_aggr<<<aggr_grid, 256, 0, stream>>>(h, rowstart, ecsr, t, n);
        k_mlp<<<mlp_grid, 256, 0, stream>>>(t, W1, B1, W2, B2, hbuf, out, n, (l + 1) * D);
    }
}

// Round 2
// 447.980 us; speedup vs baseline: 1.3243x; 1.3243x over previous
//
#include <hip/hip_runtime.h>

#define D 96
#define SCANB 512      // scan1 block size
#define ATSTR 65       // LDS transpose stride: 65 == 1 mod 32 -> conflict-free both ways

// ---------------- copy x into out[:, 0:96] ----------------
__global__ void k_copyx(const float* __restrict__ x, float* __restrict__ out, int n) {
    int idx = blockIdx.x * blockDim.x + threadIdx.x;   // n*24 float4s
    if (idx >= n * 24) return;
    int r = idx / 24, c = idx - r * 24;
    ((float4*)out)[r * 96 + c] = ((const float4*)x)[r * 24 + c];   // out row = 384 floats = 96 float4
}

// ---------------- CSR build ----------------
__global__ void k_hist(const int* __restrict__ dst, int* __restrict__ deg, int E) {
    int e = blockIdx.x * blockDim.x + threadIdx.x;
    if (e < E) atomicAdd(&deg[dst[e]], 1);
}

__global__ __launch_bounds__(SCANB) void k_scan1(const int* __restrict__ deg,
                                                 int* __restrict__ rowstart,
                                                 int* __restrict__ bsum, int n) {
    __shared__ int s[SCANB];
    int idx = threadIdx.x, gid = blockIdx.x * SCANB + idx;
    int v = (gid < n) ? deg[gid] : 0;
    s[idx] = v;
    __syncthreads();
    for (int off = 1; off < SCANB; off <<= 1) {
        int u = (idx >= off) ? s[idx - off] : 0;
        __syncthreads();
        s[idx] += u;
        __syncthreads();
    }
    if (gid < n) rowstart[gid] = s[idx] - v;            // exclusive within block
    if (idx == SCANB - 1) bsum[blockIdx.x] = s[idx];    // block total
}

__global__ void k_scan2(const int* __restrict__ bsum, int* __restrict__ boff, int nb) {
    __shared__ int s[128];
    int idx = threadIdx.x;
    int v = (idx < nb) ? bsum[idx] : 0;
    s[idx] = v;
    __syncthreads();
    for (int off = 1; off < 128; off <<= 1) {
        int u = (idx >= off) ? s[idx - off] : 0;
        __syncthreads();
        s[idx] += u;
        __syncthreads();
    }
    if (idx < nb) boff[idx] = s[idx] - v;               // exclusive across blocks
}

__global__ void k_scan3(int* __restrict__ rowstart, int* __restrict__ cursor,
                        const int* __restrict__ boff, int n, int E) {
    int gid = blockIdx.x * blockDim.x + threadIdx.x;
    if (gid < n) {
        int v = rowstart[gid] + boff[gid >> 9];         // >>9 == /SCANB
        rowstart[gid] = v;
        cursor[gid] = v;
    }
    if (gid == 0) rowstart[n] = E;
}

__global__ void k_fill(const int* __restrict__ src, const int* __restrict__ dst,
                       int* __restrict__ cursor, int* __restrict__ ecsr, int E) {
    int e = blockIdx.x * blockDim.x + threadIdx.x;
    if (e < E) {
        int p = atomicAdd(&cursor[dst[e]], 1);
        ecsr[p] = src[e];
    }
}

// ---------------- GIN aggregation: t[i] = h[i] + sum_{(s->i)} h[s] ----------------
// 32-lane group per node; lanes 0-23 each hold one float4 of the 96-float row.
// One dwordx4 gather per edge (rows are 384B = 3x128B cache lines, 128B-aligned).
__global__ __launch_bounds__(256) void k_aggr(const float* __restrict__ h,
                                              const int* __restrict__ rowstart,
                                              const int* __restrict__ ecsr,
                                              float* __restrict__ t, int n) {
    int g = (blockIdx.x * 256 + threadIdx.x) >> 5;      // node id
    int lane = threadIdx.x & 31;
    if (g >= n || lane >= 24) return;
    const float4* hp = (const float4*)h;                // 24 float4 per row
    float4 a = hp[(size_t)g * 24 + lane];               // self term (eps=0)
    int e0 = rowstart[g], e1 = rowstart[g + 1];
    int k = e0;
    for (; k + 4 <= e1; k += 4) {                       // 4 gathers in flight
        int s0 = ecsr[k], s1 = ecsr[k + 1], s2 = ecsr[k + 2], s3 = ecsr[k + 3];
        float4 v0 = hp[(size_t)s0 * 24 + lane];
        float4 v1 = hp[(size_t)s1 * 24 + lane];
        float4 v2 = hp[(size_t)s2 * 24 + lane];
        float4 v3 = hp[(size_t)s3 * 24 + lane];
        a.x += v0.x + v1.x + v2.x + v3.x;
        a.y += v0.y + v1.y + v2.y + v3.y;
        a.z += v0.z + v1.z + v2.z + v3.z;
        a.w += v0.w + v1.w + v2.w + v3.w;
    }
    for (; k < e1; k++) {
        int s = ecsr[k];
        float4 v = hp[(size_t)s * 24 + lane];
        a.x += v.x; a.y += v.y; a.z += v.z; a.w += v.w;
    }
    ((float4*)t)[(size_t)g * 24 + lane] = a;
}

// ---------------- fused MLP: h_new = relu(t@W1 + b1)@W2 + b2 ----------------
// 64 rows/block, 256 threads = 4 waves. Wave w owns output cols [24w, 24w+24).
// Weights read via wave-uniform addresses -> s_load into SGPRs (scalar pipe);
// activations k-major in LDS, 1 ds_read_b32 per k feeds 24 v_fmac (SGPR operand).
// LDS 25KB; acc[24] + misc ~ 40 VGPR.
__global__ __launch_bounds__(256) void k_mlp(const float* __restrict__ t,
                                             const float* __restrict__ W1,
                                             const float* __restrict__ B1,
                                             const float* __restrict__ W2,
                                             const float* __restrict__ B2,
                                             float* __restrict__ hbuf,
                                             float* __restrict__ out,
                                             int n, int ocol) {
    __shared__ float at[D * ATSTR];          // 96*65*4 = 24960 B

    const int tid = threadIdx.x;
    const int lane = tid & 63;               // row index within block
    const int row0 = blockIdx.x * 64;
    const int wv = __builtin_amdgcn_readfirstlane(tid >> 6);   // force wave-uniform
    const int c0 = wv * 24;

    // stage 64 rows of t, transposed: at[c*65 + r] = t[row0+r][c]  (coalesced reads,
    // writes: consecutive tid -> consecutive c -> bank (c+r)%32 consecutive, conflict-free)
    for (int idx = tid; idx < 64 * D; idx += 256) {
        int r = idx / D, c = idx - r * D;
        int gr = row0 + r; if (gr >= n) gr = n - 1;
        at[c * ATSTR + r] = t[(size_t)gr * D + c];
    }
    __syncthreads();

    float acc[24];

    // ---- pass 1: y1 = relu(t @ W1 + b1), this wave's 24 cols ----
    #pragma unroll
    for (int j = 0; j < 24; j++) acc[j] = B1[c0 + j];          // uniform -> SGPR
    #pragma unroll 4
    for (int k = 0; k < D; k++) {
        float av = at[k * ATSTR + lane];                       // lane-consecutive, 2-way (free)
        const float* wr = W1 + k * D + c0;                     // uniform -> s_load
        #pragma unroll
        for (int j = 0; j < 24; j++) acc[j] = fmaf(av, wr[j], acc[j]);
    }
    __syncthreads();                                           // all at-reads done
    #pragma unroll
    for (int j = 0; j < 24; j++)                               // y1 transposed back into at
        at[(c0 + j) * ATSTR + lane] = fmaxf(acc[j], 0.f);
    __syncthreads();

    // ---- pass 2: h = y1 @ W2 + b2 ----
    #pragma unroll
    for (int j = 0; j < 24; j++) acc[j] = B2[c0 + j];
    #pragma unroll 4
    for (int k = 0; k < D; k++) {
        float av = at[k * ATSTR + lane];
        const float* wr = W2 + k * D + c0;
        #pragma unroll
        for (int j = 0; j < 24; j++) acc[j] = fmaf(av, wr[j], acc[j]);
    }
    __syncthreads();
    #pragma unroll
    for (int j = 0; j < 24; j++)
        at[(c0 + j) * ATSTR + lane] = acc[j];
    __syncthreads();

    // coalesced store of the 64x96 result to hbuf and out
    for (int idx = tid; idx < 64 * D; idx += 256) {
        int r = idx / D, c = idx - r * D;
        int gr = row0 + r;
        if (gr < n) {
            float v = at[c * ATSTR + r];
            hbuf[(size_t)gr * D + c] = v;
            out[(size_t)gr * 384 + ocol + c] = v;
        }
    }
}

extern "C" void kernel_launch(void* const* d_in, const int* in_sizes, int n_in,
                              void* d_out, int out_size, void* d_ws, size_t ws_size,
                              hipStream_t stream) {
    const float* x = (const float*)d_in[0];
    const int* ei = (const int*)d_in[1];
    const int n = in_sizes[0] / D;           // 50000
    const int E = in_sizes[1] / 2;           // 800000
    const int* src = ei;
    const int* dst = ei + E;
    float* out = (float*)d_out;

    // workspace layout
    float* t    = (float*)d_ws;              // n*D floats
    float* hbuf = t + (size_t)n * D;         // n*D floats
    int*   deg      = (int*)(hbuf + (size_t)n * D);
    int*   rowstart = deg + 50048;           // n+1 entries
    int*   cursor   = rowstart + 50056;
    int*   bsum     = cursor + 50048;
    int*   boff     = bsum + 128;
    int*   ecsr     = boff + 128;            // E entries

    const int nb_scan = (n + SCANB - 1) / SCANB;   // 98

    // out[:,0:96] = x
    k_copyx<<<(n * 24 + 255) / 256, 256, 0, stream>>>(x, out, n);

    // CSR build (once; shared by all 3 layers)
    hipMemsetAsync(deg, 0, (size_t)n * sizeof(int), stream);
    k_hist<<<(E + 255) / 256, 256, 0, stream>>>(dst, deg, E);
    k_scan1<<<nb_scan, SCANB, 0, stream>>>(deg, rowstart, bsum, n);
    k_scan2<<<1, 128, 0, stream>>>(bsum, boff, nb_scan);
    k_scan3<<<(n + 255) / 256, 256, 0, stream>>>(rowstart, cursor, boff, n, E);
    k_fill<<<(E + 255) / 256, 256, 0, stream>>>(src, dst, cursor, ecsr, E);

    const int aggr_grid = (n * 32 + 255) / 256;
    const int mlp_grid  = (n + 63) / 64;

    for (int l = 0; l < 3; l++) {
        const float* W1 = (const float*)d_in[2 + 4 * l];
        const float* B1 = (const float*)d_in[3 + 4 * l];
        const float* W2 = (const float*)d_in[4 + 4 * l];
        const float* B2 = (const float*)d_in[5 + 4 * l];
        const float* h = (l == 0) ? x : hbuf;
        k_aggr<<<aggr_grid, 256, 0, stream>>>(h, rowstart, ecsr, t, n);
        k_mlp<<<mlp_grid, 256, 0, stream>>>(t, W1, B1, W2, B2, hbuf, out, n, (l + 1) * D);
    }
}

// Round 3
// 369.570 us; speedup vs baseline: 1.6053x; 1.2122x over previous
//
#include <hip/hip_runtime.h>
#include <hip/hip_bf16.h>

#define D 96
#define SCANB 512      // scan1 block size
#define ASTR 104       // LDS bf16 row stride (halves): 208B, 16B-aligned, 2-way banks (free)
#define WSTR 104

typedef __attribute__((ext_vector_type(8))) short short8;   // 8 bf16 = 4 VGPRs
typedef __attribute__((ext_vector_type(4))) float f32x4v;   // MFMA accumulator

// ---------------- copy x into out[:, 0:96] ----------------
__global__ void k_copyx(const float* __restrict__ x, float* __restrict__ out, int n) {
    int idx = blockIdx.x * blockDim.x + threadIdx.x;   // n*24 float4s
    if (idx >= n * 24) return;
    int r = idx / 24, c = idx - r * 24;
    ((float4*)out)[r * 96 + c] = ((const float4*)x)[r * 24 + c];
}

// ---------------- weight prep: fp32 [k][n] -> bf16 transposed [n][k] stride 104 ----------------
__global__ void k_prep(const float* __restrict__ w10, const float* __restrict__ w20,
                       const float* __restrict__ w11, const float* __restrict__ w21,
                       const float* __restrict__ w12, const float* __restrict__ w22,
                       __hip_bfloat16* __restrict__ wTg) {
    int idx = blockIdx.x * blockDim.x + threadIdx.x;   // 6*9216
    if (idx >= 6 * 9216) return;
    int m = idx / 9216, i = idx - m * 9216;
    int k = i / 96, nn = i - k * 96;
    const float* W;
    switch (m) {
        case 0: W = w10; break; case 1: W = w20; break;
        case 2: W = w11; break; case 3: W = w21; break;
        case 4: W = w12; break; default: W = w22; break;
    }
    wTg[(size_t)m * (96 * WSTR) + nn * WSTR + k] = __float2bfloat16(W[k * 96 + nn]);
}

// ---------------- CSR build ----------------
__global__ void k_hist(const int* __restrict__ dst, int* __restrict__ deg, int E) {
    int e = blockIdx.x * blockDim.x + threadIdx.x;
    if (e < E) atomicAdd(&deg[dst[e]], 1);
}

__global__ __launch_bounds__(SCANB) void k_scan1(const int* __restrict__ deg,
                                                 int* __restrict__ rowstart,
                                                 int* __restrict__ bsum, int n) {
    __shared__ int s[SCANB];
    int idx = threadIdx.x, gid = blockIdx.x * SCANB + idx;
    int v = (gid < n) ? deg[gid] : 0;
    s[idx] = v;
    __syncthreads();
    for (int off = 1; off < SCANB; off <<= 1) {
        int u = (idx >= off) ? s[idx - off] : 0;
        __syncthreads();
        s[idx] += u;
        __syncthreads();
    }
    if (gid < n) rowstart[gid] = s[idx] - v;
    if (idx == SCANB - 1) bsum[blockIdx.x] = s[idx];
}

__global__ void k_scan2(const int* __restrict__ bsum, int* __restrict__ boff, int nb) {
    __shared__ int s[128];
    int idx = threadIdx.x;
    int v = (idx < nb) ? bsum[idx] : 0;
    s[idx] = v;
    __syncthreads();
    for (int off = 1; off < 128; off <<= 1) {
        int u = (idx >= off) ? s[idx - off] : 0;
        __syncthreads();
        s[idx] += u;
        __syncthreads();
    }
    if (idx < nb) boff[idx] = s[idx] - v;
}

__global__ void k_scan3(int* __restrict__ rowstart, int* __restrict__ cursor,
                        const int* __restrict__ boff, int n, int E) {
    int gid = blockIdx.x * blockDim.x + threadIdx.x;
    if (gid < n) {
        int v = rowstart[gid] + boff[gid >> 9];
        rowstart[gid] = v;
        cursor[gid] = v;
    }
    if (gid == 0) rowstart[n] = E;
}

__global__ void k_fill(const int* __restrict__ src, const int* __restrict__ dst,
                       int* __restrict__ cursor, int* __restrict__ ecsr, int E) {
    int e = blockIdx.x * blockDim.x + threadIdx.x;
    if (e < E) {
        int p = atomicAdd(&cursor[dst[e]], 1);
        ecsr[p] = src[e];
    }
}

// ---------------- GIN aggregation: t[i] = h[i] + sum h[s]; OUTPUT bf16 ----------------
__global__ __launch_bounds__(256) void k_aggr(const float* __restrict__ h,
                                              const int* __restrict__ rowstart,
                                              const int* __restrict__ ecsr,
                                              __hip_bfloat16* __restrict__ t16, int n) {
    int g = (blockIdx.x * 256 + threadIdx.x) >> 5;      // node id
    int lane = threadIdx.x & 31;
    if (g >= n || lane >= 24) return;
    const float4* hp = (const float4*)h;                // 24 float4 per row
    float4 a = hp[(size_t)g * 24 + lane];               // self term (eps=0)
    int e0 = rowstart[g], e1 = rowstart[g + 1];
    int k = e0;
    for (; k + 4 <= e1; k += 4) {                       // 4 gathers in flight
        int s0 = ecsr[k], s1 = ecsr[k + 1], s2 = ecsr[k + 2], s3 = ecsr[k + 3];
        float4 v0 = hp[(size_t)s0 * 24 + lane];
        float4 v1 = hp[(size_t)s1 * 24 + lane];
        float4 v2 = hp[(size_t)s2 * 24 + lane];
        float4 v3 = hp[(size_t)s3 * 24 + lane];
        a.x += v0.x + v1.x + v2.x + v3.x;
        a.y += v0.y + v1.y + v2.y + v3.y;
        a.z += v0.z + v1.z + v2.z + v3.z;
        a.w += v0.w + v1.w + v2.w + v3.w;
    }
    for (; k < e1; k++) {
        int s = ecsr[k];
        float4 v = hp[(size_t)s * 24 + lane];
        a.x += v.x; a.y += v.y; a.z += v.z; a.w += v.w;
    }
    union { __hip_bfloat16 hh[4]; uint2 u; } p;
    p.hh[0] = __float2bfloat16(a.x); p.hh[1] = __float2bfloat16(a.y);
    p.hh[2] = __float2bfloat16(a.z); p.hh[3] = __float2bfloat16(a.w);
    ((uint2*)t16)[(size_t)g * 24 + lane] = p.u;         // 24 lanes x 8B = 192B row
}

// ---------------- MFMA MLP: h = relu(t@W1+b1)@W2 + b2 ----------------
// 64 rows/block, 4 waves; wave w owns 16-row band. 6 n-tiles x 3 k-steps per pass.
__global__ __launch_bounds__(256) void k_mlpm(const __hip_bfloat16* __restrict__ t16,
                                              const __hip_bfloat16* __restrict__ w1t,
                                              const float* __restrict__ B1,
                                              const __hip_bfloat16* __restrict__ w2t,
                                              const float* __restrict__ B2,
                                              float* __restrict__ hbuf,
                                              float* __restrict__ out,
                                              int n, int ocol) {
    __shared__ __align__(16) short aT[64 * ASTR];   // activations / y1, bf16
    __shared__ __align__(16) short wS[96 * WSTR];   // current weight, bf16 transposed

    const int tid = threadIdx.x;
    const int row0 = blockIdx.x * 64;
    const int lane = tid & 63;
    const int wv = __builtin_amdgcn_readfirstlane(tid >> 6);
    const int wr0 = wv * 16;                         // wave's row band
    const int quad = lane >> 4;
    const int r = lane & 15;

    // stage 64 rows of t16 (8B chunks) and W1
    {
        const uint2* tsrc = (const uint2*)t16;
        for (int idx = tid; idx < 64 * 24; idx += 256) {
            int rr = idx / 24, c = idx - rr * 24;
            int gr = row0 + rr; if (gr >= n) gr = n - 1;
            *(uint2*)&aT[rr * ASTR + c * 4] = tsrc[(size_t)gr * 24 + c];
        }
        const uint* wsrc = (const uint*)w1t;
        uint* wdst = (uint*)wS;
        for (int idx = tid; idx < 96 * WSTR / 2; idx += 256) wdst[idx] = wsrc[idx];
    }
    __syncthreads();

    // A fragments for this wave's band: A[m=r][k=quad*8+j] per 32-wide k-step
    short8 af[3];
    #pragma unroll
    for (int ksi = 0; ksi < 3; ksi++)
        af[ksi] = *(const short8*)&aT[(wr0 + r) * ASTR + ksi * 32 + quad * 8];

    // ---- pass 1 ----
    f32x4v c1[6];
    #pragma unroll
    for (int nt = 0; nt < 6; nt++) {
        f32x4v c = {0.f, 0.f, 0.f, 0.f};
        #pragma unroll
        for (int ksi = 0; ksi < 3; ksi++) {
            short8 bfr = *(const short8*)&wS[(nt * 16 + r) * WSTR + ksi * 32 + quad * 8];
            c = __builtin_amdgcn_mfma_f32_16x16x32_bf16(af[ksi], bfr, c, 0, 0, 0);
        }
        c1[nt] = c;
    }
    __syncthreads();                                 // everyone done reading W1

    // y1 = relu(c + b1) -> bf16 into own band of aT; restage W2
    #pragma unroll
    for (int nt = 0; nt < 6; nt++) {
        float bv = B1[nt * 16 + r];
        #pragma unroll
        for (int i = 0; i < 4; i++) {
            float y = fmaxf(c1[nt][i] + bv, 0.f);
            __hip_bfloat16 hb = __float2bfloat16(y);
            aT[(wr0 + quad * 4 + i) * ASTR + nt * 16 + r] = *(short*)&hb;
        }
    }
    {
        const uint* wsrc = (const uint*)w2t;
        uint* wdst = (uint*)wS;
        for (int idx = tid; idx < 96 * WSTR / 2; idx += 256) wdst[idx] = wsrc[idx];
    }
    __syncthreads();

    // ---- pass 2 ----
    short8 af2[3];
    #pragma unroll
    for (int ksi = 0; ksi < 3; ksi++)
        af2[ksi] = *(const short8*)&aT[(wr0 + r) * ASTR + ksi * 32 + quad * 8];

    #pragma unroll
    for (int nt = 0; nt < 6; nt++) {
        f32x4v c = {0.f, 0.f, 0.f, 0.f};
        #pragma unroll
        for (int ksi = 0; ksi < 3; ksi++) {
            short8 bfr = *(const short8*)&wS[(nt * 16 + r) * WSTR + ksi * 32 + quad * 8];
            c = __builtin_amdgcn_mfma_f32_16x16x32_bf16(af2[ksi], bfr, c, 0, 0, 0);
        }
        float bv = B2[nt * 16 + r];
        int col = nt * 16 + r;
        #pragma unroll
        for (int i = 0; i < 4; i++) {
            int gr = row0 + wr0 + quad * 4 + i;
            if (gr < n) {
                float v = c[i] + bv;
                hbuf[(size_t)gr * D + col] = v;
                out[(size_t)gr * 384 + ocol + col] = v;
            }
        }
    }
}

// ---------------- next-layer input: hbuf fp32 -> gather source stays fp32 ----------------

extern "C" void kernel_launch(void* const* d_in, const int* in_sizes, int n_in,
                              void* d_out, int out_size, void* d_ws, size_t ws_size,
                              hipStream_t stream) {
    const float* x = (const float*)d_in[0];
    const int* ei = (const int*)d_in[1];
    const int n = in_sizes[0] / D;           // 50000
    const int E = in_sizes[1] / 2;           // 800000
    const int* src = ei;
    const int* dst = ei + E;
    float* out = (float*)d_out;

    // workspace layout (bytes)
    char* ws = (char*)d_ws;
    __hip_bfloat16* t16 = (__hip_bfloat16*)ws;                 // n*96 halves = 9.6 MB
    float* hbuf = (float*)(ws + 9600000);                      // n*96 fp32 = 19.2 MB
    __hip_bfloat16* wTg = (__hip_bfloat16*)(ws + 28800000);    // 6*96*104 halves ~ 120 KB
    int* deg      = (int*)(ws + 28950016);
    int* rowstart = deg + 50048;             // n+1 entries
    int* cursor   = rowstart + 50056;
    int* bsum     = cursor + 50048;
    int* boff     = bsum + 128;
    int* ecsr     = boff + 128;              // E entries

    const int nb_scan = (n + SCANB - 1) / SCANB;   // 98

    // out[:,0:96] = x
    k_copyx<<<(n * 24 + 255) / 256, 256, 0, stream>>>(x, out, n);

    // weights -> bf16 transposed
    k_prep<<<(6 * 9216 + 255) / 256, 256, 0, stream>>>(
        (const float*)d_in[2], (const float*)d_in[4],
        (const float*)d_in[6], (const float*)d_in[8],
        (const float*)d_in[10], (const float*)d_in[12], wTg);

    // CSR build (once; shared by all 3 layers)
    hipMemsetAsync(deg, 0, (size_t)n * sizeof(int), stream);
    k_hist<<<(E + 255) / 256, 256, 0, stream>>>(dst, deg, E);
    k_scan1<<<nb_scan, SCANB, 0, stream>>>(deg, rowstart, bsum, n);
    k_scan2<<<1, 128, 0, stream>>>(bsum, boff, nb_scan);
    k_scan3<<<(n + 255) / 256, 256, 0, stream>>>(rowstart, cursor, boff, n, E);
    k_fill<<<(E + 255) / 256, 256, 0, stream>>>(src, dst, cursor, ecsr, E);

    const int aggr_grid = (n * 32 + 255) / 256;
    const int mlp_grid  = (n + 63) / 64;

    for (int l = 0; l < 3; l++) {
        const float* B1 = (const float*)d_in[3 + 4 * l];
        const float* B2 = (const float*)d_in[5 + 4 * l];
        const __hip_bfloat16* w1t = wTg + (size_t)(2 * l) * (96 * WSTR);
        const __hip_bfloat16* w2t = wTg + (size_t)(2 * l + 1) * (96 * WSTR);
        const float* h = (l == 0) ? x : hbuf;
        k_aggr<<<aggr_grid, 256, 0, stream>>>(h, rowstart, ecsr, t16, n);
        k_mlpm<<<mlp_grid, 256, 0, stream>>>(t16, w1t, B1, w2t, B2, hbuf, out, n, (l + 1) * D);
    }
}

// Round 4
// 328.551 us; speedup vs baseline: 1.8057x; 1.1248x over previous
//
#include <hip/hip_runtime.h>
#include <hip/hip_bf16.h>

#define D 96
#define ASTR 104       // LDS bf16 row stride (halves): 208B, 16B-aligned, 2-way banks (free)
#define WSTR 104
#define NB 512         // coarse buckets
#define NG 8           // block groups (~XCDs)
#define BPB 98         // nodes per bucket (512*98 >= 50000)

typedef __attribute__((ext_vector_type(8))) short short8;   // 8 bf16 = 4 VGPRs
typedef __attribute__((ext_vector_type(4))) float f32x4v;   // MFMA accumulator

__device__ inline float blo(unsigned u) { return __uint_as_float(u << 16); }
__device__ inline float bhi(unsigned u) { return __uint_as_float(u & 0xffff0000u); }

// ---------------- copy x into out[:, 0:96] and bf16 mirror ----------------
__global__ void k_copyx(const float* __restrict__ x, float* __restrict__ out,
                        __hip_bfloat16* __restrict__ h16, int n) {
    int idx = blockIdx.x * blockDim.x + threadIdx.x;   // n*24 float4s
    if (idx >= n * 24) return;
    int r = idx / 24, c = idx - r * 24;
    float4 v = ((const float4*)x)[r * 24 + c];
    ((float4*)out)[r * 96 + c] = v;
    union { __hip_bfloat16 hh[4]; uint2 u; } p;
    p.hh[0] = __float2bfloat16(v.x); p.hh[1] = __float2bfloat16(v.y);
    p.hh[2] = __float2bfloat16(v.z); p.hh[3] = __float2bfloat16(v.w);
    ((uint2*)h16)[r * 24 + c] = p.u;
}

// ---------------- weight prep: fp32 [k][n] -> bf16 transposed [n][k] stride 104 ----------------
__global__ void k_prep(const float* __restrict__ w10, const float* __restrict__ w20,
                       const float* __restrict__ w11, const float* __restrict__ w21,
                       const float* __restrict__ w12, const float* __restrict__ w22,
                       __hip_bfloat16* __restrict__ wTg) {
    int idx = blockIdx.x * blockDim.x + threadIdx.x;   // 6*9216
    if (idx >= 6 * 9216) return;
    int m = idx / 9216, i = idx - m * 9216;
    int k = i / 96, nn = i - k * 96;
    const float* W;
    switch (m) {
        case 0: W = w10; break; case 1: W = w20; break;
        case 2: W = w11; break; case 3: W = w21; break;
        case 4: W = w12; break; default: W = w22; break;
    }
    wTg[(size_t)m * (96 * WSTR) + nn * WSTR + k] = __float2bfloat16(W[k * 96 + nn]);
}

// ---------------- 2-level CSR build ----------------
// count edges per (bucket, group)
__global__ __launch_bounds__(256) void k_bcount(const int* __restrict__ dst,
                                                int* __restrict__ cnt, int E, int nblk) {
    __shared__ int h[NB];
    for (int i = threadIdx.x; i < NB; i += 256) h[i] = 0;
    __syncthreads();
    int g = blockIdx.x & (NG - 1);
    int chunk = (E + nblk - 1) / nblk;
    int e0 = blockIdx.x * chunk, e1 = min(e0 + chunk, E);
    for (int e = e0 + threadIdx.x; e < e1; e += 256)
        atomicAdd(&h[dst[e] / BPB], 1);
    __syncthreads();
    for (int i = threadIdx.x; i < NB; i += 256)
        if (h[i]) atomicAdd(&cnt[i * NG + g], h[i]);
}

// exclusive scan of cnt[4096] -> basearr + cursor
__global__ __launch_bounds__(256) void k_bscan(const int* __restrict__ cnt,
                                               int* __restrict__ basearr,
                                               int* __restrict__ cursor) {
    __shared__ int tot[256];
    int t = threadIdx.x;
    int v[16]; int s = 0;
    #pragma unroll
    for (int i = 0; i < 16; i++) { v[i] = cnt[t * 16 + i]; s += v[i]; }
    tot[t] = s;
    __syncthreads();
    for (int off = 1; off < 256; off <<= 1) {
        int u = (t >= off) ? tot[t - off] : 0;
        __syncthreads();
        tot[t] += u;
        __syncthreads();
    }
    int base = tot[t] - s;   // exclusive
    #pragma unroll
    for (int i = 0; i < 16; i++) {
        basearr[t * 16 + i] = base; cursor[t * 16 + i] = base; base += v[i];
    }
}

// scatter (src,dst) pairs into (bucket,group) segments — group-private cursors,
// writes combine in each group's L2
__global__ __launch_bounds__(256) void k_bscatter(const int* __restrict__ src,
                                                  const int* __restrict__ dst,
                                                  int* __restrict__ cursor,
                                                  uint2* __restrict__ epair,
                                                  int E, int nblk) {
    int g = blockIdx.x & (NG - 1);
    int chunk = (E + nblk - 1) / nblk;
    int e0 = blockIdx.x * chunk, e1 = min(e0 + chunk, E);
    for (int e = e0 + threadIdx.x; e < e1; e += 256) {
        int d = dst[e];
        int b = d / BPB;
        int p = atomicAdd(&cursor[b * NG + g], 1);
        epair[p] = make_uint2((unsigned)src[e], (unsigned)d);
    }
}

// one block per bucket: LDS histogram + scan + scatter into own ~6KB ecsr window
__global__ __launch_bounds__(256) void k_bfine(const uint2* __restrict__ epair,
                                               const int* __restrict__ basearr,
                                               int* __restrict__ rowstart,
                                               int* __restrict__ ecsr, int n, int E) {
    __shared__ int cnt[BPB];
    __shared__ int cur[BPB];
    int b = blockIdx.x;
    int nb0 = b * BPB;
    if (nb0 >= n) return;
    int nb1 = min(nb0 + BPB, n);
    int s0 = basearr[b * NG];
    int s1 = (b == NB - 1) ? E : basearr[(b + 1) * NG];
    for (int i = threadIdx.x; i < BPB; i += 256) cnt[i] = 0;
    __syncthreads();
    for (int e = s0 + threadIdx.x; e < s1; e += 256)
        atomicAdd(&cnt[(int)epair[e].y - nb0], 1);
    __syncthreads();
    if (threadIdx.x == 0) {
        int run = s0;
        for (int i = 0; i < nb1 - nb0; i++) { cur[i] = run; run += cnt[i]; }
    }
    __syncthreads();
    for (int i = threadIdx.x; i < nb1 - nb0; i += 256) rowstart[nb0 + i] = cur[i];
    if (threadIdx.x == 0 && nb1 == n) rowstart[n] = s1;   // s1 == E for the last bucket
    __syncthreads();                                       // rowstart reads of cur done before mutation
    for (int e = s0 + threadIdx.x; e < s1; e += 256) {
        uint2 p = epair[e];
        int pos = atomicAdd(&cur[(int)p.y - nb0], 1);
        ecsr[pos] = (int)p.x;
    }
}

// ---------------- GIN aggregation (bf16 rows): t[i] = h[i] + sum h[s] ----------------
// 32-lane group per node; lanes 0-23 each hold one dwordx2 (4 bf16) of the 192B row.
__global__ __launch_bounds__(256) void k_aggr(const __hip_bfloat16* __restrict__ h16,
                                              const int* __restrict__ rowstart,
                                              const int* __restrict__ ecsr,
                                              __hip_bfloat16* __restrict__ t16, int n) {
    int g = (blockIdx.x * 256 + threadIdx.x) >> 5;      // node id
    int lane = threadIdx.x & 31;
    if (g >= n || lane >= 24) return;
    const uint2* hp = (const uint2*)h16;                // 24 uint2 per row
    uint2 u = hp[(size_t)g * 24 + lane];                // self term (eps=0)
    float ax = blo(u.x), ay = bhi(u.x), az = blo(u.y), aw = bhi(u.y);
    int e0 = rowstart[g], e1 = rowstart[g + 1];
    int k = e0;
    for (; k + 4 <= e1; k += 4) {                       // 4 gathers in flight
        int s0 = ecsr[k], s1 = ecsr[k + 1], s2 = ecsr[k + 2], s3 = ecsr[k + 3];
        uint2 v0 = hp[(size_t)s0 * 24 + lane];
        uint2 v1 = hp[(size_t)s1 * 24 + lane];
        uint2 v2 = hp[(size_t)s2 * 24 + lane];
        uint2 v3 = hp[(size_t)s3 * 24 + lane];
        ax += blo(v0.x) + blo(v1.x) + blo(v2.x) + blo(v3.x);
        ay += bhi(v0.x) + bhi(v1.x) + bhi(v2.x) + bhi(v3.x);
        az += blo(v0.y) + blo(v1.y) + blo(v2.y) + blo(v3.y);
        aw += bhi(v0.y) + bhi(v1.y) + bhi(v2.y) + bhi(v3.y);
    }
    for (; k < e1; k++) {
        int s = ecsr[k];
        uint2 v = hp[(size_t)s * 24 + lane];
        ax += blo(v.x); ay += bhi(v.x); az += blo(v.y); aw += bhi(v.y);
    }
    union { __hip_bfloat16 hh[4]; uint2 uu; } p;
    p.hh[0] = __float2bfloat16(ax); p.hh[1] = __float2bfloat16(ay);
    p.hh[2] = __float2bfloat16(az); p.hh[3] = __float2bfloat16(aw);
    ((uint2*)t16)[(size_t)g * 24 + lane] = p.uu;
}

// ---------------- MFMA MLP: h = relu(t@W1+b1)@W2 + b2 ----------------
// 64 rows/block, 4 waves; wave w owns 16-row band. 6 n-tiles x 3 k-steps per pass.
__global__ __launch_bounds__(256) void k_mlpm(const __hip_bfloat16* __restrict__ t16,
                                              const __hip_bfloat16* __restrict__ w1t,
                                              const float* __restrict__ B1,
                                              const __hip_bfloat16* __restrict__ w2t,
                                              const float* __restrict__ B2,
                                              __hip_bfloat16* __restrict__ h16,
                                              float* __restrict__ out,
                                              int n, int ocol) {
    __shared__ __align__(16) short aT[64 * ASTR];   // activations / y1, bf16
    __shared__ __align__(16) short wS[96 * WSTR];   // current weight, bf16 transposed

    const int tid = threadIdx.x;
    const int row0 = blockIdx.x * 64;
    const int lane = tid & 63;
    const int wv = __builtin_amdgcn_readfirstlane(tid >> 6);
    const int wr0 = wv * 16;                         // wave's row band
    const int quad = lane >> 4;
    const int r = lane & 15;

    // stage 64 rows of t16 (8B chunks) and W1
    {
        const uint2* tsrc = (const uint2*)t16;
        for (int idx = tid; idx < 64 * 24; idx += 256) {
            int rr = idx / 24, c = idx - rr * 24;
            int gr = row0 + rr; if (gr >= n) gr = n - 1;
            *(uint2*)&aT[rr * ASTR + c * 4] = tsrc[(size_t)gr * 24 + c];
        }
        const unsigned* wsrc = (const unsigned*)w1t;
        unsigned* wdst = (unsigned*)wS;
        for (int idx = tid; idx < 96 * WSTR / 2; idx += 256) wdst[idx] = wsrc[idx];
    }
    __syncthreads();

    // A fragments: A[m=r][k=quad*8+j]
    short8 af[3];
    #pragma unroll
    for (int ksi = 0; ksi < 3; ksi++)
        af[ksi] = *(const short8*)&aT[(wr0 + r) * ASTR + ksi * 32 + quad * 8];

    // ---- pass 1 ----
    f32x4v c1[6];
    #pragma unroll
    for (int nt = 0; nt < 6; nt++) {
        f32x4v c = {0.f, 0.f, 0.f, 0.f};
        #pragma unroll
        for (int ksi = 0; ksi < 3; ksi++) {
            short8 bfr = *(const short8*)&wS[(nt * 16 + r) * WSTR + ksi * 32 + quad * 8];
            c = __builtin_amdgcn_mfma_f32_16x16x32_bf16(af[ksi], bfr, c, 0, 0, 0);
        }
        c1[nt] = c;
    }
    __syncthreads();                                 // everyone done reading W1

    // y1 = relu(c + b1) -> bf16 into own band of aT; restage W2
    #pragma unroll
    for (int nt = 0; nt < 6; nt++) {
        float bv = B1[nt * 16 + r];
        #pragma unroll
        for (int i = 0; i < 4; i++) {
            float y = fmaxf(c1[nt][i] + bv, 0.f);
            __hip_bfloat16 hb = __float2bfloat16(y);
            aT[(wr0 + quad * 4 + i) * ASTR + nt * 16 + r] = *(short*)&hb;
        }
    }
    {
        const unsigned* wsrc = (const unsigned*)w2t;
        unsigned* wdst = (unsigned*)wS;
        for (int idx = tid; idx < 96 * WSTR / 2; idx += 256) wdst[idx] = wsrc[idx];
    }
    __syncthreads();

    // ---- pass 2 ----
    short8 af2[3];
    #pragma unroll
    for (int ksi = 0; ksi < 3; ksi++)
        af2[ksi] = *(const short8*)&aT[(wr0 + r) * ASTR + ksi * 32 + quad * 8];

    #pragma unroll
    for (int nt = 0; nt < 6; nt++) {
        f32x4v c = {0.f, 0.f, 0.f, 0.f};
        #pragma unroll
        for (int ksi = 0; ksi < 3; ksi++) {
            short8 bfr = *(const short8*)&wS[(nt * 16 + r) * WSTR + ksi * 32 + quad * 8];
            c = __builtin_amdgcn_mfma_f32_16x16x32_bf16(af2[ksi], bfr, c, 0, 0, 0);
        }
        float bv = B2[nt * 16 + r];
        int col = nt * 16 + r;
        #pragma unroll
        for (int i = 0; i < 4; i++) {
            int gr = row0 + wr0 + quad * 4 + i;
            if (gr < n) {
                float v = c[i] + bv;
                out[(size_t)gr * 384 + ocol + col] = v;
                h16[(size_t)gr * D + col] = __float2bfloat16(v);
            }
        }
    }
}

extern "C" void kernel_launch(void* const* d_in, const int* in_sizes, int n_in,
                              void* d_out, int out_size, void* d_ws, size_t ws_size,
                              hipStream_t stream) {
    const float* x = (const float*)d_in[0];
    const int* ei = (const int*)d_in[1];
    const int n = in_sizes[0] / D;           // 50000
    const int E = in_sizes[1] / 2;           // 800000
    const int* src = ei;
    const int* dst = ei + E;
    float* out = (float*)d_out;

    // workspace layout (byte offsets, all 16B-aligned)
    char* ws = (char*)d_ws;
    __hip_bfloat16* t16  = (__hip_bfloat16*)ws;                  // n*96 halves = 9.6 MB
    __hip_bfloat16* h16  = (__hip_bfloat16*)(ws + 9600000);      // n*96 halves = 9.6 MB
    __hip_bfloat16* wTg  = (__hip_bfloat16*)(ws + 19200000);     // 6*96*104 halves ~ 120 KB
    int*   cnt      = (int*)(ws + 19380000);                     // 4096
    int*   basearr  = (int*)(ws + 19400000);                     // 4096
    int*   cursor   = (int*)(ws + 19420000);                     // 4096
    int*   rowstart = (int*)(ws + 19440000);                     // n+1
    uint2* epair    = (uint2*)(ws + 19700000);                   // E pairs = 6.4 MB
    int*   ecsr     = (int*)(ws + 26100000);                     // E ints = 3.2 MB

    const int NBLK = 256;                    // partition blocks for bcount/bscatter

    // out[:,0:96] = x ; h16 = bf16(x)
    k_copyx<<<(n * 24 + 255) / 256, 256, 0, stream>>>(x, out, h16, n);

    // weights -> bf16 transposed
    k_prep<<<(6 * 9216 + 255) / 256, 256, 0, stream>>>(
        (const float*)d_in[2], (const float*)d_in[4],
        (const float*)d_in[6], (const float*)d_in[8],
        (const float*)d_in[10], (const float*)d_in[12], wTg);

    // 2-level CSR build (once; shared by all 3 layers)
    hipMemsetAsync(cnt, 0, NB * NG * sizeof(int), stream);
    k_bcount<<<NBLK, 256, 0, stream>>>(dst, cnt, E, NBLK);
    k_bscan<<<1, 256, 0, stream>>>(cnt, basearr, cursor);
    k_bscatter<<<NBLK, 256, 0, stream>>>(src, dst, cursor, epair, E, NBLK);
    k_bfine<<<NB, 256, 0, stream>>>(epair, basearr, rowstart, ecsr, n, E);

    const int aggr_grid = (n * 32 + 255) / 256;
    const int mlp_grid  = (n + 63) / 64;

    for (int l = 0; l < 3; l++) {
        const float* B1 = (const float*)d_in[3 + 4 * l];
        const float* B2 = (const float*)d_in[5 + 4 * l];
        const __hip_bfloat16* w1t = wTg + (size_t)(2 * l) * (96 * WSTR);
        const __hip_bfloat16* w2t = wTg + (size_t)(2 * l + 1) * (96 * WSTR);
        k_aggr<<<aggr_grid, 256, 0, stream>>>(h16, rowstart, ecsr, t16, n);
        k_mlpm<<<mlp_grid, 256, 0, stream>>>(t16, w1t, B1, w2t, B2, h16, out, n, (l + 1) * D);
    }
}